// Round 1
// baseline (36.433 us; speedup 1.0000x reference)
//
#include <hip/hip_runtime.h>
#include <hip/hip_bf16.h>

typedef __attribute__((ext_vector_type(4))) float f32x4;
typedef __attribute__((ext_vector_type(8))) short s16x8;
typedef __attribute__((ext_vector_type(4))) short s16x4;

#define KVBLK 64
#define DHEAD 128
#define KSTR 136   // K LDS row stride in bf16 elems (272 B, 16B-aligned, conflict-floor reads)
#define VSTR 72    // V^T LDS row stride in bf16 elems (144 B)

__device__ __forceinline__ short f2bf(float x) {
    __hip_bfloat16 h = __float2bfloat16(x);
    return *reinterpret_cast<short*>(&h);
}

__global__ __launch_bounds__(128, 2)
void attn_fwd(const float* __restrict__ Q, const float* __restrict__ K,
              const float* __restrict__ V, const int* __restrict__ VL,
              float* __restrict__ O, int B, int n, int m) {
    __shared__ short Ks[KVBLK * KSTR];   // K tile, row-major [kv][d]
    __shared__ short Vs[DHEAD * VSTR];   // V^T tile [dv][kv], XOR-swizzled

    const int tid  = threadIdx.x;
    const int lane = tid & 63;
    const int wid  = tid >> 6;     // 0..1
    const int g    = lane >> 4;    // 0..3
    const int qi   = lane & 15;

    // block decode with XCD-aware swizzle (keep one batch's K/V on one XCD's L2)
    int bid = blockIdx.x;
    const int nq = n >> 5;         // q-tiles of 32 rows
    int b, qt;
    if ((B & 7) == 0) {
        const int xcd = bid & 7;
        const int sub = bid >> 3;
        const int bpx = B >> 3;
        b  = xcd * bpx + (sub % bpx);
        qt = sub / bpx;
    } else {
        b = bid / nq; qt = bid - b * nq;
    }

    const int vl = VL[b];
    const float* Qb = Q + ((size_t)b * n + (size_t)qt * 32 + wid * 16) * DHEAD;
    const float* Kb = K + (size_t)b * m * DHEAD;
    const float* Vb = V + (size_t)b * m * DHEAD;

    // ---- Q fragments in registers, pre-scaled by 1/sqrt(d)*log2(e) (base-2 softmax) ----
    const float qsc = 0.08838834764831845f * 1.4426950408889634f;
    s16x8 qf[4];
    {
        const float* qp = Qb + qi * DHEAD + g * 8;
        #pragma unroll
        for (int kk = 0; kk < 4; ++kk) {
            f32x4 a = *reinterpret_cast<const f32x4*>(qp + kk * 32);
            f32x4 c = *reinterpret_cast<const f32x4*>(qp + kk * 32 + 4);
            s16x8 s;
            #pragma unroll
            for (int j = 0; j < 4; ++j) { s[j] = f2bf(a[j] * qsc); s[4 + j] = f2bf(c[j] * qsc); }
            qf[kk] = s;
        }
    }

    // per-lane V^T read bases (element offsets, swizzle folded in)
    int voff[8];
    #pragma unroll
    for (int dg = 0; dg < 8; ++dg) {
        const int row = qi + (dg << 4);
        voff[dg] = row * VSTR + ((g << 2) ^ (((row >> 3) & 3) << 2));
    }
    const int kbase = qi * KSTR + (g << 3);

    f32x4 Oacc[8];
    #pragma unroll
    for (int dg = 0; dg < 8; ++dg) Oacc[dg] = 0.f;
    float mrun = -1e30f, lrun = 0.f;

    const int ntiles = (vl + KVBLK - 1) >> 6;

    #pragma unroll 1
    for (int t = 0; t < ntiles; ++t) {
        const int base = t << 6;
        __syncthreads();
        // ---- stage K tile 64x128 -> bf16 LDS ----
        {
            const float* kp = Kb + (size_t)base * DHEAD;
            #pragma unroll
            for (int i = 0; i < 8; ++i) {
                const int c   = tid + (i << 7);
                const int row = c >> 4;
                const int d0  = (c & 15) << 3;
                f32x4 a  = *reinterpret_cast<const f32x4*>(kp + row * DHEAD + d0);
                f32x4 cc = *reinterpret_cast<const f32x4*>(kp + row * DHEAD + d0 + 4);
                s16x8 s;
                #pragma unroll
                for (int j = 0; j < 4; ++j) { s[j] = f2bf(a[j]); s[4 + j] = f2bf(cc[j]); }
                *reinterpret_cast<s16x8*>(&Ks[row * KSTR + d0]) = s;
            }
        }
        // ---- stage V tile transposed: V^T[dv][kv], swizzled columns ----
        {
            const float* vp = Vb + (size_t)base * DHEAD;
            #pragma unroll
            for (int i = 0; i < 4; ++i) {
                const int c  = tid + (i << 7);
                const int rq = c >> 5;    // kv quad 0..15
                const int dq = c & 31;    // dv quad 0..31
                const float* src = vp + (rq * 4) * DHEAD + dq * 4;
                f32x4 r0 = *reinterpret_cast<const f32x4*>(src);
                f32x4 r1 = *reinterpret_cast<const f32x4*>(src + DHEAD);
                f32x4 r2 = *reinterpret_cast<const f32x4*>(src + 2 * DHEAD);
                f32x4 r3 = *reinterpret_cast<const f32x4*>(src + 3 * DHEAD);
                #pragma unroll
                for (int jj = 0; jj < 4; ++jj) {
                    const int dvr = dq * 4 + jj;
                    s16x4 s;
                    s[0] = f2bf(r0[jj]); s[1] = f2bf(r1[jj]);
                    s[2] = f2bf(r2[jj]); s[3] = f2bf(r3[jj]);
                    const int eoff = dvr * VSTR + ((rq << 2) ^ (((dvr >> 3) & 3) << 2));
                    *reinterpret_cast<s16x4*>(&Vs[eoff]) = s;
                }
            }
        }
        __syncthreads();

        // ---- S^T = K * Q^T : rows kv (16s+4g+r), col q = qi ----
        f32x4 Sacc[4];
        #pragma unroll
        for (int s = 0; s < 4; ++s) Sacc[s] = 0.f;
        #pragma unroll
        for (int s = 0; s < 4; ++s) {
            #pragma unroll
            for (int kk = 0; kk < 4; ++kk) {
                s16x8 kf = *reinterpret_cast<const s16x8*>(&Ks[kbase + s * 16 * KSTR + kk * 32]);
                Sacc[s] = __builtin_amdgcn_mfma_f32_16x16x32_bf16(kf, qf[kk], Sacc[s], 0, 0, 0);
            }
        }

        // ---- valid_length mask ----
        const int kvrem = vl - base;
        if (kvrem < KVBLK) {
            #pragma unroll
            for (int s = 0; s < 4; ++s)
                #pragma unroll
                for (int r = 0; r < 4; ++r)
                    if (s * 16 + g * 4 + r >= kvrem) Sacc[s][r] = -1e30f;
        }

        // ---- online softmax, state per lane for q = qi (replicated x4 groups) ----
        float tmax = -1e30f;
        #pragma unroll
        for (int s = 0; s < 4; ++s)
            #pragma unroll
            for (int r = 0; r < 4; ++r) tmax = fmaxf(tmax, Sacc[s][r]);
        tmax = fmaxf(tmax, __shfl_xor(tmax, 16));
        tmax = fmaxf(tmax, __shfl_xor(tmax, 32));
        const float mnew = fmaxf(mrun, tmax);
        const float corr = __builtin_amdgcn_exp2f(mrun - mnew);

        float p[4][4];
        float psum = 0.f;
        #pragma unroll
        for (int s = 0; s < 4; ++s)
            #pragma unroll
            for (int r = 0; r < 4; ++r) {
                const float e = __builtin_amdgcn_exp2f(Sacc[s][r] - mnew);
                p[s][r] = e; psum += e;
            }
        psum += __shfl_xor(psum, 16);
        psum += __shfl_xor(psum, 32);
        lrun = lrun * corr + psum;
        mrun = mnew;

        // pack P -> bf16 A-fragments (kv-permutation consistent with V^T reads)
        s16x8 pa[2];
        #pragma unroll
        for (int h = 0; h < 2; ++h)
            #pragma unroll
            for (int r = 0; r < 4; ++r) {
                pa[h][r]     = f2bf(p[2 * h][r]);
                pa[h][4 + r] = f2bf(p[2 * h + 1][r]);
            }

        // rescale O accumulators (rows q' = 4g+r need corr from lane q')
        const float rr0 = __shfl(corr, g * 4 + 0);
        const float rr1 = __shfl(corr, g * 4 + 1);
        const float rr2 = __shfl(corr, g * 4 + 2);
        const float rr3 = __shfl(corr, g * 4 + 3);
        #pragma unroll
        for (int dg = 0; dg < 8; ++dg) {
            Oacc[dg][0] *= rr0; Oacc[dg][1] *= rr1;
            Oacc[dg][2] *= rr2; Oacc[dg][3] *= rr3;
        }

        // ---- O += P * V ----
        #pragma unroll
        for (int dg = 0; dg < 8; ++dg) {
            #pragma unroll
            for (int kk = 0; kk < 2; ++kk) {
                s16x4 v0 = *reinterpret_cast<const s16x4*>(&Vs[voff[dg] + (kk << 5)]);
                s16x4 v1 = *reinterpret_cast<const s16x4*>(&Vs[voff[dg] + (kk << 5) + 16]);
                s16x8 vf;
                vf[0] = v0[0]; vf[1] = v0[1]; vf[2] = v0[2]; vf[3] = v0[3];
                vf[4] = v1[0]; vf[5] = v1[1]; vf[6] = v1[2]; vf[7] = v1[3];
                Oacc[dg] = __builtin_amdgcn_mfma_f32_16x16x32_bf16(pa[kk], vf, Oacc[dg], 0, 0, 0);
            }
        }
    }

    // ---- epilogue: divide by l, write fp32 ----
    const float linv = 1.0f / lrun;
    const float l0 = __shfl(linv, g * 4 + 0);
    const float l1 = __shfl(linv, g * 4 + 1);
    const float l2 = __shfl(linv, g * 4 + 2);
    const float l3 = __shfl(linv, g * 4 + 3);
    float* Ob = O + ((size_t)b * n + (size_t)qt * 32 + wid * 16) * DHEAD;
    #pragma unroll
    for (int dg = 0; dg < 8; ++dg) {
        Ob[(g * 4 + 0) * DHEAD + dg * 16 + qi] = Oacc[dg][0] * l0;
        Ob[(g * 4 + 1) * DHEAD + dg * 16 + qi] = Oacc[dg][1] * l1;
        Ob[(g * 4 + 2) * DHEAD + dg * 16 + qi] = Oacc[dg][2] * l2;
        Ob[(g * 4 + 3) * DHEAD + dg * 16 + qi] = Oacc[dg][3] * l3;
    }
}

extern "C" void kernel_launch(void* const* d_in, const int* in_sizes, int n_in,
                              void* d_out, int out_size, void* d_ws, size_t ws_size,
                              hipStream_t stream) {
    const float* Q  = (const float*)d_in[0];
    const float* K  = (const float*)d_in[1];
    const float* V  = (const float*)d_in[2];
    const int*   VL = (const int*)d_in[3];
    float* O = (float*)d_out;

    const int B = in_sizes[3];
    const int n = in_sizes[0] / (B * DHEAD);
    const int m = in_sizes[1] / (B * DHEAD);

    const int grid = B * (n / 32);
    attn_fwd<<<grid, 128, 0, stream>>>(Q, K, V, VL, O, B, n, m);
}